// Round 9
// baseline (15575.981 us; speedup 1.0000x reference)
//
#include <hip/hip_runtime.h>
#include <math.h>

#define TT 4096
#define HH 1500
#define NB 250     // blocks; each owns 6 hidden units
#define NT 448     // 7 waves: 0..5 matvec (wave = unit, 4 gate rows each),
                   //          6 = x-proj + gates + publish

typedef unsigned uv4 __attribute__((ext_vector_type(4)));

#define ALD4(p)   __hip_atomic_load((p), __ATOMIC_RELAXED, __HIP_MEMORY_SCOPE_AGENT)
#define AST4(p,v) __hip_atomic_store((p), (v), __ATOMIC_RELAXED, __HIP_MEMORY_SCOPE_AGENT)

__device__ __forceinline__ float fast_sigmoid(float z) {
  return 1.0f / (1.0f + __expf(-z));
}
__device__ __forceinline__ float fast_tanh(float z) {
  float az = fabsf(z);
  float e  = __expf(-2.0f * az);
  float r  = (1.0f - e) / (1.0f + e);
  return copysignf(r, z);
}

// R5 13.2 / R7 12.5 / R8 12.7 ms: all ~7300 cy/step regardless of exchange
// structure -> the floor is the publish->poll->LDS-stage->barrier->re-read
// chain. R9: matvec waves load h(t) DIRECTLY from the exchange buffer with
// device-scope dwordx4 (the fragment layout IS the coalesced layout), tag-
// check in-register, FMA immediately. No LDS h staging, no barrier A, no
// poller waves. All 24 weight float4s prefetched to VGPRs under the poll.
__global__
__attribute__((amdgpu_flat_work_group_size(NT, NT), amdgpu_waves_per_eu(2, 2)))
void lstm_fused(
    const float* __restrict__ x,    // (4096, 20)
    const float* __restrict__ Wih,  // (6000, 20)
    const float* __restrict__ Whh,  // (6000, 1500)
    const float* __restrict__ bih,  // (6000,)
    const float* __restrict__ bhh,  // (6000,)
    const float* __restrict__ W1,   // (1875, 1500)
    const float* __restrict__ b1,   // (1875,)
    const float* __restrict__ W2,   // (20, 1875)
    const float* __restrict__ b2,   // (20,)
    float* __restrict__ out,        // (20,)
    unsigned* __restrict__ ws)
{
  const int tid = threadIdx.x;
  const int bid = blockIdx.x;
  const int wv  = tid >> 6;   // wave 0..6
  const int ln  = tid & 63;

  unsigned* pub  = ws;          // [2][1536] tagged dwords; block b owns 6b..6b+5
  unsigned* hidp = ws + 4096;   // [1875] tagged hid values

  // 24 rows x 384 float4; row r = u*4+g (u=unit, g=gate). 147,456 B
  __shared__ __align__(16) float lds_w[24 * 1536];
  __shared__ __align__(16) float lds_h[1536];   // h(TT) for MLP only
  __shared__ float lds_gs[4][6];                // gate sums: [g][u]
  float* lds_hd = lds_w;                        // alias (block 0, post-loop)

  // ---- stage W_hh slice into LDS ----
  {
    const float4* whh4 = (const float4*)Whh;
    float4* w4 = (float4*)lds_w;
    for (int idx = tid; idx < 24 * 384; idx += NT) {
      const int r = idx / 384, k4 = idx - r * 384;
      const int u = r >> 2, g = r & 3;
      const int grow = g * HH + bid * 6 + u;
      w4[idx] = (k4 < 375) ? whh4[(size_t)grow * 375 + k4]
                           : make_float4(0.f, 0.f, 0.f, 0.f);
    }
  }

  // matvec row bases (waves 0..5)
  const int uu = (wv < 6) ? wv : 0;
  const float4* wr0 = (const float4*)lds_w + (size_t)(uu * 4 + 0) * 384;
  const float4* wr1 = (const float4*)lds_w + (size_t)(uu * 4 + 1) * 384;
  const float4* wr2 = (const float4*)lds_w + (size_t)(uu * 4 + 2) * 384;
  const float4* wr3 = (const float4*)lds_w + (size_t)(uu * 4 + 3) * 384;

  // ---- wave 6 lanes 0..23: persistent Wih row (g=ln/6, u=ln%6) + x(0) ----
  float4 wx0, wx1, wx2, wx3, wx4;
  float4 xr0, xr1, xr2, xr3, xr4;
  float bias = 0.f;
  if (wv == 6 && ln < 24) {
    const int g = ln / 6, u = ln - g * 6;
    const int row = g * HH + bid * 6 + u;
    const float4* s = (const float4*)(Wih + row * 20);
    wx0 = s[0]; wx1 = s[1]; wx2 = s[2]; wx3 = s[3]; wx4 = s[4];
    bias = bih[row] + bhh[row];
    const float4* xx = (const float4*)x;
    xr0 = xx[0]; xr1 = xx[1]; xr2 = xx[2]; xr3 = xx[3]; xr4 = xx[4];
  }

  float c = 0.f;  // cell state: wave 6 lanes 0..5 (unit = ln)

  // init publish: h(0)=0 with tag 1 (tag(h(k)) = (k+1)&15)
  if (tid < 6) AST4(pub + 6 * bid + tid, 1u);

  __syncthreads();   // weights staged

  for (int t = 0; t < TT; ++t) {
    const int s = t & 1;
    const unsigned tag = (unsigned)((t + 1) & 15);

    if (wv < 6) {
      // ---- prefetch ALL 24 weight float4 (96 VGPRs) ----
      float4 qw[24];
      #pragma unroll
      for (int g = 0; g < 4; ++g) {
        const float4* wr = (g == 0) ? wr0 : (g == 1) ? wr1 : (g == 2) ? wr2 : wr3;
        #pragma unroll
        for (int m = 0; m < 6; ++m) qw[g * 6 + m] = wr[ln + 64 * m];
      }
      asm volatile("" ::: "memory");   // keep LDS loads above the poll

      // ---- direct tagged poll of h(t): 6 coalesced dwordx4, device scope ----
      const unsigned* bp  = pub + (size_t)s * 1536 + 4 * ln;
      const unsigned* bp2 = bp + 1024;
      uv4 h0, h1, h2, h3, h4v, h5;
      for (;;) {
        asm volatile(
          "global_load_dwordx4 %0, %6, off sc1\n\t"
          "global_load_dwordx4 %1, %6, off offset:1024 sc1\n\t"
          "global_load_dwordx4 %2, %6, off offset:2048 sc1\n\t"
          "global_load_dwordx4 %3, %6, off offset:3072 sc1\n\t"
          "global_load_dwordx4 %4, %7, off sc1\n\t"
          "global_load_dwordx4 %5, %7, off offset:1024 sc1\n\t"
          "s_waitcnt vmcnt(0)"
          : "=v"(h0), "=v"(h1), "=v"(h2), "=v"(h3), "=v"(h4v), "=v"(h5)
          : "v"(bp), "v"(bp2)
          : "memory");
        unsigned miss = ((h0.x & 15u) ^ tag) | ((h0.y & 15u) ^ tag) |
                        ((h0.z & 15u) ^ tag) | ((h0.w & 15u) ^ tag);
        miss |= ((h1.x & 15u) ^ tag) | ((h1.y & 15u) ^ tag) |
                ((h1.z & 15u) ^ tag) | ((h1.w & 15u) ^ tag);
        miss |= ((h2.x & 15u) ^ tag) | ((h2.y & 15u) ^ tag) |
                ((h2.z & 15u) ^ tag) | ((h2.w & 15u) ^ tag);
        miss |= ((h3.x & 15u) ^ tag) | ((h3.y & 15u) ^ tag) |
                ((h3.z & 15u) ^ tag) | ((h3.w & 15u) ^ tag);
        miss |= ((h4v.x & 15u) ^ tag) | ((h4v.y & 15u) ^ tag) |
                ((h4v.z & 15u) ^ tag) | ((h4v.w & 15u) ^ tag);
        if (ln < 55) {   // float4 idx ln+320 < 375 -> valid data
          miss |= ((h5.x & 15u) ^ tag) | ((h5.y & 15u) ^ tag) |
                  ((h5.z & 15u) ^ tag) | ((h5.w & 15u) ^ tag);
        }
        if (!__any(miss != 0u)) break;
        __builtin_amdgcn_s_sleep(1);
      }
      float4 hf[6];
      hf[0] = make_float4(__uint_as_float(h0.x), __uint_as_float(h0.y),
                          __uint_as_float(h0.z), __uint_as_float(h0.w));
      hf[1] = make_float4(__uint_as_float(h1.x), __uint_as_float(h1.y),
                          __uint_as_float(h1.z), __uint_as_float(h1.w));
      hf[2] = make_float4(__uint_as_float(h2.x), __uint_as_float(h2.y),
                          __uint_as_float(h2.z), __uint_as_float(h2.w));
      hf[3] = make_float4(__uint_as_float(h3.x), __uint_as_float(h3.y),
                          __uint_as_float(h3.z), __uint_as_float(h3.w));
      hf[4] = make_float4(__uint_as_float(h4v.x), __uint_as_float(h4v.y),
                          __uint_as_float(h4v.z), __uint_as_float(h4v.w));
      hf[5] = (ln < 55)
            ? make_float4(__uint_as_float(h5.x), __uint_as_float(h5.y),
                          __uint_as_float(h5.z), __uint_as_float(h5.w))
            : make_float4(0.f, 0.f, 0.f, 0.f);

      float a[4];
      #pragma unroll
      for (int g = 0; g < 4; ++g) {
        float sum = 0.f;
        #pragma unroll
        for (int m = 0; m < 6; ++m) {
          const float4 q = qw[g * 6 + m], hv = hf[m];
          sum = fmaf(q.x, hv.x, sum); sum = fmaf(q.y, hv.y, sum);
          sum = fmaf(q.z, hv.z, sum); sum = fmaf(q.w, hv.w, sum);
        }
        a[g] = sum;
      }
      // fold-select reduce
      #pragma unroll
      for (int g = 0; g < 4; ++g) {
        a[g] += __shfl_xor(a[g], 16, 64);
        a[g] += __shfl_xor(a[g], 32, 64);
      }
      const int q4 = ln >> 4;
      float v = (q4 == 0) ? a[0] : (q4 == 1) ? a[1] : (q4 == 2) ? a[2] : a[3];
      v += __shfl_xor(v, 1, 64);
      v += __shfl_xor(v, 2, 64);
      v += __shfl_xor(v, 4, 64);
      v += __shfl_xor(v, 8, 64);
      if ((ln & 15) == 0) lds_gs[q4][wv] = v;
    }

    float xi = 0.f, xf = 0.f, xg = 0.f, xo = 0.f;
    if (wv == 6) {
      // x-projection for step t (regs, h-independent)
      float xpv = 0.f;
      if (ln < 24) {
        float sx = bias;
        sx += wx0.x*xr0.x + wx0.y*xr0.y + wx0.z*xr0.z + wx0.w*xr0.w;
        sx += wx1.x*xr1.x + wx1.y*xr1.y + wx1.z*xr1.z + wx1.w*xr1.w;
        sx += wx2.x*xr2.x + wx2.y*xr2.y + wx2.z*xr2.z + wx2.w*xr2.w;
        sx += wx3.x*xr3.x + wx3.y*xr3.y + wx3.z*xr3.z + wx3.w*xr3.w;
        sx += wx4.x*xr4.x + wx4.y*xr4.y + wx4.z*xr4.z + wx4.w*xr4.w;
        xpv = sx;
      }
      xi = __shfl(xpv, ln, 64);        // g=0, unit ln
      xf = __shfl(xpv, ln + 6, 64);
      xg = __shfl(xpv, ln + 12, 64);
      xo = __shfl(xpv, ln + 18, 64);
    }
    __syncthreads();   // the ONLY barrier per step: gate sums ready

    if (wv == 6) {
      if (ln < 6) {
        const int u = ln;
        const float zi = lds_gs[0][u] + xi;
        const float zf = lds_gs[1][u] + xf;
        const float zg = lds_gs[2][u] + xg;
        const float zo = lds_gs[3][u] + xo;
        const float ig = fast_sigmoid(zi);
        const float fg = fast_sigmoid(zf);
        const float gg = fast_tanh(zg);
        const float og = fast_sigmoid(zo);
        c = fg * c + ig * gg;
        const float hn = og * fast_tanh(c);
        const unsigned bits = (__float_as_uint(hn) & ~15u) | (unsigned)((t + 2) & 15);
        AST4(pub + ((t + 1) & 1) * 1536 + 6 * bid + u, bits);  // ONE 24B store
      }
      if (ln < 24 && (t + 1) < TT) {   // prefetch x(t+1)
        const float4* xx = (const float4*)(x + 20 * (t + 1));
        xr0 = xx[0]; xr1 = xx[1]; xr2 = xx[2]; xr3 = xx[3]; xr4 = xx[4];
      }
    }
  }

  // ---- gather h(TT) into lds_h (slot 0, tag 1): wave wv owns chunk wv ----
  if (wv < 6) {
    const int fi = ln + 64 * wv;
    const unsigned* bp = pub + 4 * fi;
    uv4 hx;
    for (;;) {
      asm volatile("global_load_dwordx4 %0, %1, off sc1\n\ts_waitcnt vmcnt(0)"
                   : "=v"(hx) : "v"(bp) : "memory");
      unsigned miss = 0u;
      if (fi < 375) {
        miss = ((hx.x & 15u) ^ 1u) | ((hx.y & 15u) ^ 1u) |
               ((hx.z & 15u) ^ 1u) | ((hx.w & 15u) ^ 1u);
      }
      if (!__any(miss != 0u)) break;
      __builtin_amdgcn_s_sleep(1);
    }
    float4 hfv = (fi < 375)
               ? make_float4(__uint_as_float(hx.x), __uint_as_float(hx.y),
                             __uint_as_float(hx.z), __uint_as_float(hx.w))
               : make_float4(0.f, 0.f, 0.f, 0.f);
    ((float4*)lds_h)[fi] = hfv;
  }
  __syncthreads();

  // ---- MLP layer 1: rows r = bid + 250*i, i = wv (+7 for wave 0) ----
  {
    const float4* h4 = (const float4*)lds_h;
    for (int i = wv; i < 8; i += 7) {
      const int r = bid + 250 * i;
      if (r < 1875) {
        const float4* wrow = (const float4*)(W1 + (size_t)r * HH);
        float ss = 0.f;
        #pragma unroll
        for (int m = 0; m < 6; ++m) {
          const int idx = ln + 64 * m;
          if (idx < 375) {
            const float4 a = wrow[idx], hv = h4[idx];
            ss += a.x*hv.x + a.y*hv.y + a.z*hv.z + a.w*hv.w;
          }
        }
        #pragma unroll
        for (int off = 32; off > 0; off >>= 1) ss += __shfl_xor(ss, off, 64);
        if (ln == 0) {
          const float vv = ss + b1[r];
          AST4(hidp + r, (__float_as_uint(vv) & ~15u) | 5u);  // tag 5 != poison 10
        }
      }
    }
  }
  if (bid != 0) return;

  // ---- block 0: gather hid (into lds_w alias), MLP layer 2, write out ----
  __syncthreads();
  for (int j = tid; j < 1875; j += NT) {
    unsigned bts;
    for (;;) {
      bts = ALD4(hidp + j);
      if ((bts & 15u) == 5u) break;
      __builtin_amdgcn_s_sleep(1);
    }
    lds_hd[j] = __uint_as_float(bts);
  }
  __syncthreads();

  for (int r = wv; r < 20; r += 7) {
    float ss = 0.f;
    for (int k = ln; k < 1875; k += 64)
      ss = fmaf(W2[(size_t)r * 1875 + k], lds_hd[k], ss);
    #pragma unroll
    for (int off = 32; off > 0; off >>= 1) ss += __shfl_xor(ss, off, 64);
    if (ln == 0) out[r] = ss + b2[r];
  }
}

extern "C" void kernel_launch(void* const* d_in, const int* in_sizes, int n_in,
                              void* d_out, int out_size, void* d_ws, size_t ws_size,
                              hipStream_t stream) {
  const float* x   = (const float*)d_in[0];
  const float* Wih = (const float*)d_in[1];
  const float* Whh = (const float*)d_in[2];
  const float* bih = (const float*)d_in[3];
  const float* bhh = (const float*)d_in[4];
  const float* W1  = (const float*)d_in[5];
  const float* b1  = (const float*)d_in[6];
  const float* W2  = (const float*)d_in[7];
  const float* b2  = (const float*)d_in[8];
  float* out   = (float*)d_out;
  unsigned* ws = (unsigned*)d_ws;   // uses ~24 KB

  // 250 blocks x 448 threads, ~154 KB LDS -> 1 block/CU, 250 <= 256 CUs:
  // all blocks co-resident -> the tagged exchange cannot deadlock.
  hipLaunchKernelGGL(lstm_fused, dim3(NB), dim3(NT), 0, stream,
                     x, Wih, Whh, bih, bhh, W1, b1, W2, b2, out, ws);
}

// Round 10
// 12003.717 us; speedup vs baseline: 1.2976x; 1.2976x over previous
//
#include <hip/hip_runtime.h>
#include <math.h>

#define TT 4096
#define HH 1500
#define NB 250     // blocks; each owns 6 hidden units
#define NT 512     // 8 waves: 0..5 matvec (wave = unit, 4 gate rows each),
                   //          6 = x-proj + poll, 7 = poll + gates + publish

typedef unsigned uv4 __attribute__((ext_vector_type(4)));
typedef _Float16 h2f __attribute__((ext_vector_type(2)));

#define ALD4(p)   __hip_atomic_load((p), __ATOMIC_RELAXED, __HIP_MEMORY_SCOPE_AGENT)
#define AST4(p,v) __hip_atomic_store((p), (v), __ATOMIC_RELAXED, __HIP_MEMORY_SCOPE_AGENT)

__device__ __forceinline__ float fast_sigmoid(float z) {
  return 1.0f / (1.0f + __expf(-z));
}
__device__ __forceinline__ float fast_tanh(float z) {
  float az = fabsf(z);
  float e  = __expf(-2.0f * az);
  float r  = (1.0f - e) / (1.0f + e);
  return copysignf(r, z);
}
// fp16 pair dot with fp32 accumulate (v_dot2_f32_f16)
__device__ __forceinline__ float dot2(unsigned wb, unsigned hb, float acc) {
#if __has_builtin(__builtin_amdgcn_fdot2)
  return __builtin_amdgcn_fdot2(__builtin_bit_cast(h2f, wb),
                                __builtin_bit_cast(h2f, hb), acc, false);
#else
  h2f w = __builtin_bit_cast(h2f, wb), h = __builtin_bit_cast(h2f, hb);
  acc = fmaf((float)w.x, (float)h.x, acc);
  return fmaf((float)w.y, (float)h.y, acc);
#endif
}

// R5 13.2 / R6 21.2 / R7 12.5 / R8 12.7 / R9 15.6 ms. R9 showed the exchange
// is contention-sensitive (more pollers = slower). R8 budget: ~2.6k cy/step of
// serialized DS-pipe (180 ds_read_b128 weight stream + reduce swizzles) on top
// of the exchange RT. R10 = R8 skeleton with W_hh and h in fp16 (LDS halves to
// ~83 KB, kept >80 KiB to force 1 block/CU) and v_dot2_f32_f16 matvec (fp32
// accumulate -> per-gate err ~5e-5). 90 b128/step/CU instead of 180.
__global__
__attribute__((amdgpu_flat_work_group_size(NT, NT), amdgpu_waves_per_eu(2, 2)))
void lstm_fused(
    const float* __restrict__ x,    // (4096, 20)
    const float* __restrict__ Wih,  // (6000, 20)
    const float* __restrict__ Whh,  // (6000, 1500)
    const float* __restrict__ bih,  // (6000,)
    const float* __restrict__ bhh,  // (6000,)
    const float* __restrict__ W1,   // (1875, 1500)
    const float* __restrict__ b1,   // (1875,)
    const float* __restrict__ W2,   // (20, 1875)
    const float* __restrict__ b2,   // (20,)
    float* __restrict__ out,        // (20,)
    unsigned* __restrict__ ws)
{
  const int tid = threadIdx.x;
  const int bid = blockIdx.x;
  const int wv  = tid >> 6;   // wave 0..7
  const int ln  = tid & 63;

  unsigned* pub  = ws;          // [2][1536] tagged dwords; block b owns 6b..6b+5
  unsigned* hidp = ws + 4096;   // [1875] tagged hid values

  // weights: 24 rows (r=u*4+g) x 1536 halves (1500 + zero pad) = 73,728 B
  __shared__ __align__(16) _Float16 lds_wh[24 * 1536];
  __shared__ __align__(16) _Float16 lds_hh[1536];  // h(t) as fp16
  __shared__ __align__(16) float    lds_hf[1536];  // h(TT) fp32 for MLP
  __shared__ float lds_xp[2][24];                  // x-proj dbuf: [par][g*6+u]
  __shared__ float lds_gs[4][6];                   // gate sums: [g][u]
  float* lds_hd = (float*)lds_wh;                  // alias (block 0, post-loop)
  // total ~83.1 KB > 80 KiB -> exactly 1 block/CU (lockstep chain intact)

  // ---- stage W_hh slice into LDS, converting fp32 -> fp16 ----
  for (int hi = tid; hi < 24 * 1536; hi += NT) {
    const int r = hi / 1536, k = hi - r * 1536;
    const int u = r >> 2, g = r & 3;
    const size_t grow = (size_t)(g * HH + bid * 6 + u) * HH;
    const float v = (k < HH) ? Whh[grow + k] : 0.f;
    lds_wh[hi] = (_Float16)v;
  }

  // matvec bases (waves 0..5): 192 b128-chunks per row
  const int uu = (wv < 6) ? wv : 0;
  const uv4* wp = ((const uv4*)lds_wh) + (size_t)uu * 4 * 192;
  const uv4* hp = (const uv4*)lds_hh;

  // ---- wave 6 lanes 0..23: persistent Wih row (g=ln/6, u=ln%6) + x(0) ----
  float4 wx0, wx1, wx2, wx3, wx4;
  float4 xr0, xr1, xr2, xr3, xr4;
  float bias = 0.f;
  if (wv == 6 && ln < 24) {
    const int g = ln / 6, u = ln - g * 6;
    const int row = g * HH + bid * 6 + u;
    const float4* s = (const float4*)(Wih + row * 20);
    wx0 = s[0]; wx1 = s[1]; wx2 = s[2]; wx3 = s[3]; wx4 = s[4];
    bias = bih[row] + bhh[row];
    const float4* xx = (const float4*)x;
    xr0 = xx[0]; xr1 = xx[1]; xr2 = xx[2]; xr3 = xx[3]; xr4 = xx[4];
  }

  float c = 0.f;  // cell state: wave 7 lanes 0..5 (unit = ln)

  // init publish: h(0)=0 with tag 1 (tag(h(k)) = (k+1)&15)
  if (tid < 6) AST4(pub + 6 * bid + tid, 1u);

  __syncthreads();   // weights staged

  for (int t = 0; t < TT; ++t) {
    const int s = t & 1;
    const unsigned tag = (unsigned)((t + 1) & 15);

    // ================= P phase (pre-A) =================
    uv4 pw[12];
    if (wv < 6) {
      // prefetch ALL 12 weight b128 (48 VGPRs) — overlaps the poll below
      #pragma unroll
      for (int g = 0; g < 4; ++g) {
        #pragma unroll
        for (int m = 0; m < 3; ++m) pw[g * 3 + m] = wp[g * 192 + ln + 64 * m];
      }
    } else {
      if (wv == 6 && ln < 24) {
        // x-projection for step t (from registers, h-independent)
        float sx = bias;
        sx += wx0.x*xr0.x + wx0.y*xr0.y + wx0.z*xr0.z + wx0.w*xr0.w;
        sx += wx1.x*xr1.x + wx1.y*xr1.y + wx1.z*xr1.z + wx1.w*xr1.w;
        sx += wx2.x*xr2.x + wx2.y*xr2.y + wx2.z*xr2.z + wx2.w*xr2.w;
        sx += wx3.x*xr3.x + wx3.y*xr3.y + wx3.z*xr3.z + wx3.w*xr3.w;
        sx += wx4.x*xr4.x + wx4.y*xr4.y + wx4.z*xr4.z + wx4.w*xr4.w;
        lds_xp[s][ln] = sx;
      }
      // ---- coalesced tagged poll: lane p owns dwords p+128k, k=0..11 ----
      const int p = tid - 384;               // 0..127
      unsigned* base = pub + s * 1536;
      unsigned vals[12];
      for (;;) {
        unsigned miss = 0u;
        #pragma unroll
        for (int k = 0; k < 12; ++k) {
          const int idx = p + 128 * k;
          vals[k] = ALD4(base + idx);
          if (idx < HH) miss |= (vals[k] & 15u) ^ tag;
        }
        if (!__any(miss != 0u)) break;
        __builtin_amdgcn_s_sleep(1);
      }
      #pragma unroll
      for (int k = 0; k < 12; ++k) {
        const int idx = p + 128 * k;
        lds_hh[idx] = (idx < HH) ? (_Float16)__uint_as_float(vals[k])
                                 : (_Float16)0.f;
      }
    }
    __syncthreads();   // ---- A: h(t) fp16, xp(t) staged ----

    // ================= M phase =================
    if (wv < 6) {
      uv4 hv[3];
      #pragma unroll
      for (int m = 0; m < 3; ++m) hv[m] = hp[ln + 64 * m];
      float a[4] = {0.f, 0.f, 0.f, 0.f};
      #pragma unroll
      for (int g = 0; g < 4; ++g) {
        #pragma unroll
        for (int m = 0; m < 3; ++m) {
          const uv4 q = pw[g * 3 + m], h = hv[m];
          a[g] = dot2(q.x, h.x, a[g]);
          a[g] = dot2(q.y, h.y, a[g]);
          a[g] = dot2(q.z, h.z, a[g]);
          a[g] = dot2(q.w, h.w, a[g]);
        }
      }
      // fold-select reduce: 12 swizzles + 1 ds_write
      #pragma unroll
      for (int g = 0; g < 4; ++g) {
        a[g] += __shfl_xor(a[g], 16, 64);
        a[g] += __shfl_xor(a[g], 32, 64);
      }
      const int q4 = ln >> 4;
      float v = (q4 == 0) ? a[0] : (q4 == 1) ? a[1] : (q4 == 2) ? a[2] : a[3];
      v += __shfl_xor(v, 1, 64);
      v += __shfl_xor(v, 2, 64);
      v += __shfl_xor(v, 4, 64);
      v += __shfl_xor(v, 8, 64);
      if ((ln & 15) == 0) lds_gs[q4][wv] = v;
    } else if (wv == 6 && ln < 24 && (t + 1) < TT) {
      // prefetch x(t+1) while waves 0-5 compute
      const float4* xx = (const float4*)(x + 20 * (t + 1));
      xr0 = xx[0]; xr1 = xx[1]; xr2 = xx[2]; xr3 = xx[3]; xr4 = xx[4];
    }
    __syncthreads();   // ---- B: gate sums ready ----

    // ================= G phase: wave 7 only =================
    if (wv == 7 && ln < 6) {
      const int u = ln;
      const float zi = lds_gs[0][u] + lds_xp[s][0 + u];
      const float zf = lds_gs[1][u] + lds_xp[s][6 + u];
      const float zg = lds_gs[2][u] + lds_xp[s][12 + u];
      const float zo = lds_gs[3][u] + lds_xp[s][18 + u];
      const float ig = fast_sigmoid(zi);
      const float fg = fast_sigmoid(zf);
      const float gg = fast_tanh(zg);
      const float og = fast_sigmoid(zo);
      c = fg * c + ig * gg;
      const float hn = og * fast_tanh(c);
      const unsigned bits = (__float_as_uint(hn) & ~15u) | (unsigned)((t + 2) & 15);
      AST4(pub + ((t + 1) & 1) * 1536 + 6 * bid + u, bits);  // ONE 24B store
    }
  }

  // ---- final gather h(TT) fp32 into lds_hf (slot 0, tag 1) ----
  if (wv >= 6) {
    const unsigned tagf = (unsigned)((TT + 1) & 15);
    const int p = tid - 384;
    unsigned* base = pub;
    unsigned vals[12];
    for (;;) {
      unsigned miss = 0u;
      #pragma unroll
      for (int k = 0; k < 12; ++k) {
        const int idx = p + 128 * k;
        vals[k] = ALD4(base + idx);
        if (idx < HH) miss |= (vals[k] & 15u) ^ tagf;
      }
      if (!__any(miss != 0u)) break;
      __builtin_amdgcn_s_sleep(1);
    }
    #pragma unroll
    for (int k = 0; k < 12; ++k) {
      const int idx = p + 128 * k;
      lds_hf[idx] = (idx < HH) ? __uint_as_float(vals[k]) : 0.f;
    }
  }
  __syncthreads();

  // ---- MLP layer 1: wave wv computes row r = bid + 250*wv ----
  {
    const float4* h4 = (const float4*)lds_hf;
    const int r = bid + 250 * wv;
    if (r < 1875) {
      const float4* wrow = (const float4*)(W1 + (size_t)r * HH);
      float ss = 0.f;
      #pragma unroll
      for (int m = 0; m < 6; ++m) {
        const int idx = ln + 64 * m;
        if (idx < 375) {
          const float4 a = wrow[idx], hv = h4[idx];
          ss += a.x*hv.x + a.y*hv.y + a.z*hv.z + a.w*hv.w;
        }
      }
      #pragma unroll
      for (int off = 32; off > 0; off >>= 1) ss += __shfl_xor(ss, off, 64);
      if (ln == 0) {
        const float vv = ss + b1[r];
        AST4(hidp + r, (__float_as_uint(vv) & ~15u) | 5u);  // tag 5 != poison 10
      }
    }
  }
  if (bid != 0) return;

  // ---- block 0: gather hid (into lds_wh alias), MLP layer 2, write out ----
  __syncthreads();
  for (int j = tid; j < 1875; j += NT) {
    unsigned bts;
    for (;;) {
      bts = ALD4(hidp + j);
      if ((bts & 15u) == 5u) break;
      __builtin_amdgcn_s_sleep(1);
    }
    lds_hd[j] = __uint_as_float(bts);
  }
  __syncthreads();

  for (int r = wv; r < 20; r += 8) {
    float ss = 0.f;
    for (int k = ln; k < 1875; k += 64)
      ss = fmaf(W2[(size_t)r * 1875 + k], lds_hd[k], ss);
    #pragma unroll
    for (int off = 32; off > 0; off >>= 1) ss += __shfl_xor(ss, off, 64);
    if (ln == 0) out[r] = ss + b2[r];
  }
}

extern "C" void kernel_launch(void* const* d_in, const int* in_sizes, int n_in,
                              void* d_out, int out_size, void* d_ws, size_t ws_size,
                              hipStream_t stream) {
  const float* x   = (const float*)d_in[0];
  const float* Wih = (const float*)d_in[1];
  const float* Whh = (const float*)d_in[2];
  const float* bih = (const float*)d_in[3];
  const float* bhh = (const float*)d_in[4];
  const float* W1  = (const float*)d_in[5];
  const float* b1  = (const float*)d_in[6];
  const float* W2  = (const float*)d_in[7];
  const float* b2  = (const float*)d_in[8];
  float* out   = (float*)d_out;
  unsigned* ws = (unsigned*)d_ws;   // uses ~24 KB

  // 250 blocks x 512 threads, ~83 KB LDS (>80 KiB -> 1 block/CU), 250 <= 256
  // CUs: all blocks co-resident -> the tagged exchange cannot deadlock.
  hipLaunchKernelGGL(lstm_fused, dim3(NB), dim3(NT), 0, stream,
                     x, Wih, Whh, bih, bhh, W1, b1, W2, b2, out, ws);
}

// Round 11
// 10473.254 us; speedup vs baseline: 1.4872x; 1.1461x over previous
//
#include <hip/hip_runtime.h>
#include <math.h>

#define TT 4096
#define HH 1500
#define NB 250     // blocks; each owns 6 hidden units
#define NT 512     // 8 waves: 0..5 matvec (wave = unit, 4 gate rows each),
                   //          6 = x-proj + poll, 7 = poll + gates + publish
#define NREP 8     // pub replicas (reader sharding)

typedef unsigned uv4 __attribute__((ext_vector_type(4)));
typedef _Float16 h2f __attribute__((ext_vector_type(2)));

#define ALD4(p)   __hip_atomic_load((p), __ATOMIC_RELAXED, __HIP_MEMORY_SCOPE_AGENT)
#define AST4(p,v) __hip_atomic_store((p), (v), __ATOMIC_RELAXED, __HIP_MEMORY_SCOPE_AGENT)

__device__ __forceinline__ float fast_sigmoid(float z) {
  return 1.0f / (1.0f + __expf(-z));
}
__device__ __forceinline__ float fast_tanh(float z) {
  float az = fabsf(z);
  float e  = __expf(-2.0f * az);
  float r  = (1.0f - e) / (1.0f + e);
  return copysignf(r, z);
}
// fp16 pair dot with fp32 accumulate (v_dot2_f32_f16)
__device__ __forceinline__ float dot2(unsigned wb, unsigned hb, float acc) {
#if __has_builtin(__builtin_amdgcn_fdot2)
  return __builtin_amdgcn_fdot2(__builtin_bit_cast(h2f, wb),
                                __builtin_bit_cast(h2f, hb), acc, false);
#else
  h2f w = __builtin_bit_cast(h2f, wb), h = __builtin_bit_cast(h2f, hb);
  acc = fmaf((float)w.x, (float)h.x, acc);
  return fmaf((float)w.y, (float)h.y, acc);
#endif
}

// R10 12.0ms: ~7030 cy/step, of which <=2000 is compute/barriers -> ~5000 cy
// handoff. Diagnosis: all 250 blocks poll the SAME 96 pub lines; per-line
// read serialization at the LLC slice (~250 readers x ~2-4cy) is the drain.
// Evidence: R9 more-pollers regression; R8 per-consumer coalescing neutral.
// R11: 8 replicas of the pub buffer. Publisher: wave 7 lanes 0..47 store one
// dword each (8 x 24B to 8 DISTINCT lines - not R6's hot-line fragmentation).
// Consumers poll replica bid&7 -> ~31 readers/line instead of 250.
__global__
__attribute__((amdgpu_flat_work_group_size(NT, NT), amdgpu_waves_per_eu(2, 2)))
void lstm_fused(
    const float* __restrict__ x,    // (4096, 20)
    const float* __restrict__ Wih,  // (6000, 20)
    const float* __restrict__ Whh,  // (6000, 1500)
    const float* __restrict__ bih,  // (6000,)
    const float* __restrict__ bhh,  // (6000,)
    const float* __restrict__ W1,   // (1875, 1500)
    const float* __restrict__ b1,   // (1875,)
    const float* __restrict__ W2,   // (20, 1875)
    const float* __restrict__ b2,   // (20,)
    float* __restrict__ out,        // (20,)
    unsigned* __restrict__ ws)
{
  const int tid = threadIdx.x;
  const int bid = blockIdx.x;
  const int wv  = tid >> 6;   // wave 0..7
  const int ln  = tid & 63;

  // pub: [NREP][2][1536] tagged dwords; block b owns dwords 6b..6b+5 of each
  // replica/slot. hidp after.
  unsigned* pub  = ws;
  unsigned* hidp = ws + NREP * 2 * 1536;   // [1875] tagged hid values

  // weights: 24 rows (r=u*4+g) x 1536 halves (1500 + zero pad) = 73,728 B
  __shared__ __align__(16) _Float16 lds_wh[24 * 1536];
  __shared__ __align__(16) _Float16 lds_hh[1536];  // h(t) as fp16
  __shared__ __align__(16) float    lds_hf[1536];  // h(TT) fp32 for MLP
  __shared__ float lds_xp[2][24];                  // x-proj dbuf: [par][g*6+u]
  __shared__ float lds_gs[4][6];                   // gate sums: [g][u]
  float* lds_hd = (float*)lds_wh;                  // alias (block 0, post-loop)
  // total ~83.1 KB > 80 KiB -> exactly 1 block/CU (lockstep chain intact)

  // ---- stage W_hh slice into LDS, converting fp32 -> fp16 ----
  for (int hi = tid; hi < 24 * 1536; hi += NT) {
    const int r = hi / 1536, k = hi - r * 1536;
    const int u = r >> 2, g = r & 3;
    const size_t grow = (size_t)(g * HH + bid * 6 + u) * HH;
    const float v = (k < HH) ? Whh[grow + k] : 0.f;
    lds_wh[hi] = (_Float16)v;
  }

  // matvec bases (waves 0..5): 192 b128-chunks per row
  const int uu = (wv < 6) ? wv : 0;
  const uv4* wp = ((const uv4*)lds_wh) + (size_t)uu * 4 * 192;
  const uv4* hp = (const uv4*)lds_hh;

  // ---- wave 6 lanes 0..23: persistent Wih row (g=ln/6, u=ln%6) + x(0) ----
  float4 wx0, wx1, wx2, wx3, wx4;
  float4 xr0, xr1, xr2, xr3, xr4;
  float bias = 0.f;
  if (wv == 6 && ln < 24) {
    const int g = ln / 6, u = ln - g * 6;
    const int row = g * HH + bid * 6 + u;
    const float4* s = (const float4*)(Wih + row * 20);
    wx0 = s[0]; wx1 = s[1]; wx2 = s[2]; wx3 = s[3]; wx4 = s[4];
    bias = bih[row] + bhh[row];
    const float4* xx = (const float4*)x;
    xr0 = xx[0]; xr1 = xx[1]; xr2 = xx[2]; xr3 = xx[3]; xr4 = xx[4];
  }

  float c = 0.f;  // cell state: wave 7 lanes 0..5 (unit = ln)

  // init publish: h(0)=0 with tag 1 into ALL replicas, slot 0
  if (tid < 6 * NREP)
    AST4(pub + (tid / 6) * 3072 + 6 * bid + (tid % 6), 1u);

  __syncthreads();   // weights staged

  // this block's poll replica
  unsigned* myrep = pub + (bid & (NREP - 1)) * 3072;

  for (int t = 0; t < TT; ++t) {
    const int s = t & 1;
    const unsigned tag = (unsigned)((t + 1) & 15);

    // ================= P phase (pre-A) =================
    uv4 pw[12];
    if (wv < 6) {
      // prefetch ALL 12 weight b128 (48 VGPRs) — overlaps the poll below
      #pragma unroll
      for (int g = 0; g < 4; ++g) {
        #pragma unroll
        for (int m = 0; m < 3; ++m) pw[g * 3 + m] = wp[g * 192 + ln + 64 * m];
      }
    } else {
      if (wv == 6 && ln < 24) {
        // x-projection for step t (from registers, h-independent)
        float sx = bias;
        sx += wx0.x*xr0.x + wx0.y*xr0.y + wx0.z*xr0.z + wx0.w*xr0.w;
        sx += wx1.x*xr1.x + wx1.y*xr1.y + wx1.z*xr1.z + wx1.w*xr1.w;
        sx += wx2.x*xr2.x + wx2.y*xr2.y + wx2.z*xr2.z + wx2.w*xr2.w;
        sx += wx3.x*xr3.x + wx3.y*xr3.y + wx3.z*xr3.z + wx3.w*xr3.w;
        sx += wx4.x*xr4.x + wx4.y*xr4.y + wx4.z*xr4.z + wx4.w*xr4.w;
        lds_xp[s][ln] = sx;
      }
      // ---- coalesced tagged poll of replica bid&7 ----
      const int p = tid - 384;               // 0..127
      unsigned* base = myrep + s * 1536;
      unsigned vals[12];
      for (;;) {
        unsigned miss = 0u;
        #pragma unroll
        for (int k = 0; k < 12; ++k) {
          const int idx = p + 128 * k;
          vals[k] = ALD4(base + idx);
          if (idx < HH) miss |= (vals[k] & 15u) ^ tag;
        }
        if (!__any(miss != 0u)) break;
        __builtin_amdgcn_s_sleep(1);
      }
      #pragma unroll
      for (int k = 0; k < 12; ++k) {
        const int idx = p + 128 * k;
        lds_hh[idx] = (idx < HH) ? (_Float16)__uint_as_float(vals[k])
                                 : (_Float16)0.f;
      }
    }
    __syncthreads();   // ---- A: h(t) fp16, xp(t) staged ----

    // ================= M phase =================
    if (wv < 6) {
      uv4 hv[3];
      #pragma unroll
      for (int m = 0; m < 3; ++m) hv[m] = hp[ln + 64 * m];
      float a[4] = {0.f, 0.f, 0.f, 0.f};
      #pragma unroll
      for (int g = 0; g < 4; ++g) {
        #pragma unroll
        for (int m = 0; m < 3; ++m) {
          const uv4 q = pw[g * 3 + m], h = hv[m];
          a[g] = dot2(q.x, h.x, a[g]);
          a[g] = dot2(q.y, h.y, a[g]);
          a[g] = dot2(q.z, h.z, a[g]);
          a[g] = dot2(q.w, h.w, a[g]);
        }
      }
      // fold-select reduce: 12 swizzles + 1 ds_write
      #pragma unroll
      for (int g = 0; g < 4; ++g) {
        a[g] += __shfl_xor(a[g], 16, 64);
        a[g] += __shfl_xor(a[g], 32, 64);
      }
      const int q4 = ln >> 4;
      float v = (q4 == 0) ? a[0] : (q4 == 1) ? a[1] : (q4 == 2) ? a[2] : a[3];
      v += __shfl_xor(v, 1, 64);
      v += __shfl_xor(v, 2, 64);
      v += __shfl_xor(v, 4, 64);
      v += __shfl_xor(v, 8, 64);
      if ((ln & 15) == 0) lds_gs[q4][wv] = v;
    } else if (wv == 6 && ln < 24 && (t + 1) < TT) {
      // prefetch x(t+1) while waves 0-5 compute
      const float4* xx = (const float4*)(x + 20 * (t + 1));
      xr0 = xx[0]; xr1 = xx[1]; xr2 = xx[2]; xr3 = xx[3]; xr4 = xx[4];
    }
    __syncthreads();   // ---- B: gate sums ready ----

    // ================= G phase: wave 7 only =================
    if (wv == 7) {
      unsigned bits = 0u;
      if (ln < 6) {
        const int u = ln;
        const float zi = lds_gs[0][u] + lds_xp[s][0 + u];
        const float zf = lds_gs[1][u] + lds_xp[s][6 + u];
        const float zg = lds_gs[2][u] + lds_xp[s][12 + u];
        const float zo = lds_gs[3][u] + lds_xp[s][18 + u];
        const float ig = fast_sigmoid(zi);
        const float fg = fast_sigmoid(zf);
        const float gg = fast_tanh(zg);
        const float og = fast_sigmoid(zo);
        c = fg * c + ig * gg;
        const float hn = og * fast_tanh(c);
        bits = (__float_as_uint(hn) & ~15u) | (unsigned)((t + 2) & 15);
      }
      // broadcast 6 tagged dwords to lanes 0..47; store to all 8 replicas
      const int u6 = ln % 6;
      const unsigned myb = (unsigned)__shfl((int)bits, u6, 64);
      if (ln < 6 * NREP) {
        const int rep = ln / 6;
        AST4(pub + rep * 3072 + ((t + 1) & 1) * 1536 + 6 * bid + u6, myb);
      }
    }
  }

  // ---- final gather h(TT) fp32 into lds_hf (slot 0, tag 1) ----
  if (wv >= 6) {
    const unsigned tagf = (unsigned)((TT + 1) & 15);
    const int p = tid - 384;
    unsigned* base = myrep;   // slot 0 of own replica
    unsigned vals[12];
    for (;;) {
      unsigned miss = 0u;
      #pragma unroll
      for (int k = 0; k < 12; ++k) {
        const int idx = p + 128 * k;
        vals[k] = ALD4(base + idx);
        if (idx < HH) miss |= (vals[k] & 15u) ^ tagf;
      }
      if (!__any(miss != 0u)) break;
      __builtin_amdgcn_s_sleep(1);
    }
    #pragma unroll
    for (int k = 0; k < 12; ++k) {
      const int idx = p + 128 * k;
      lds_hf[idx] = (idx < HH) ? __uint_as_float(vals[k]) : 0.f;
    }
  }
  __syncthreads();

  // ---- MLP layer 1: wave wv computes row r = bid + 250*wv ----
  {
    const float4* h4 = (const float4*)lds_hf;
    const int r = bid + 250 * wv;
    if (r < 1875) {
      const float4* wrow = (const float4*)(W1 + (size_t)r * HH);
      float ss = 0.f;
      #pragma unroll
      for (int m = 0; m < 6; ++m) {
        const int idx = ln + 64 * m;
        if (idx < 375) {
          const float4 a = wrow[idx], hv = h4[idx];
          ss += a.x*hv.x + a.y*hv.y + a.z*hv.z + a.w*hv.w;
        }
      }
      #pragma unroll
      for (int off = 32; off > 0; off >>= 1) ss += __shfl_xor(ss, off, 64);
      if (ln == 0) {
        const float vv = ss + b1[r];
        AST4(hidp + r, (__float_as_uint(vv) & ~15u) | 5u);  // tag 5 != poison 10
      }
    }
  }
  if (bid != 0) return;

  // ---- block 0: gather hid (into lds_wh alias), MLP layer 2, write out ----
  __syncthreads();
  for (int j = tid; j < 1875; j += NT) {
    unsigned bts;
    for (;;) {
      bts = ALD4(hidp + j);
      if ((bts & 15u) == 5u) break;
      __builtin_amdgcn_s_sleep(1);
    }
    lds_hd[j] = __uint_as_float(bts);
  }
  __syncthreads();

  for (int r = wv; r < 20; r += 8) {
    float ss = 0.f;
    for (int k = ln; k < 1875; k += 64)
      ss = fmaf(W2[(size_t)r * 1875 + k], lds_hd[k], ss);
    #pragma unroll
    for (int off = 32; off > 0; off >>= 1) ss += __shfl_xor(ss, off, 64);
    if (ln == 0) out[r] = ss + b2[r];
  }
}

extern "C" void kernel_launch(void* const* d_in, const int* in_sizes, int n_in,
                              void* d_out, int out_size, void* d_ws, size_t ws_size,
                              hipStream_t stream) {
  const float* x   = (const float*)d_in[0];
  const float* Wih = (const float*)d_in[1];
  const float* Whh = (const float*)d_in[2];
  const float* bih = (const float*)d_in[3];
  const float* bhh = (const float*)d_in[4];
  const float* W1  = (const float*)d_in[5];
  const float* b1  = (const float*)d_in[6];
  const float* W2  = (const float*)d_in[7];
  const float* b2  = (const float*)d_in[8];
  float* out   = (float*)d_out;
  unsigned* ws = (unsigned*)d_ws;   // uses ~106 KB (8 pub replicas + hidp)

  // 250 blocks x 512 threads, ~83 KB LDS (>80 KiB -> 1 block/CU), 250 <= 256
  // CUs: all blocks co-resident -> the tagged exchange cannot deadlock.
  hipLaunchKernelGGL(lstm_fused, dim3(NB), dim3(NT), 0, stream,
                     x, Wih, Whh, bih, bhh, W1, b1, W2, b2, out, ws);
}